// Round 1
// baseline (312.954 us; speedup 1.0000x reference)
//
#include <hip/hip_runtime.h>

// relative_depth_crit — R5: tile-sweep gather.
// R1-R4 pinned the bottleneck to a per-CU scattered-vmem request cap
// (~0.237 req/cyc/CU, insensitive to MLP / L1 bypass / occupancy / LDS-DMA
// scatter). R5 eliminates scattered global requests entirely: stream each
// batch's 1.31 MB depth image through LDS in 64 KB tiles (coalesced
// global_load_lds dwordx4, BW-bound not token-bound) and resolve gathers as
// exec-masked ds_read_b32 against register-held offsets (56/thread).
// Block = 512 thr owns 12500 points of one batch; grid 512 = 64 batches x 8
// chunks; 1 block/CU (128 KB LDS), 2 rounds. Batch's 8 blocks pinned to one
// XCD so each tile is L3-fetched once and L2-hit by the other 7 blocks.

constexpr int B = 64;
constexpr int H = 512;
constexpr int W = 640;
constexpr int P = 100000;
constexpr int HWSZ = H * W;            // 327680 floats = 1.31 MB per batch
constexpr int N4B = P / 4;             // 25000 vec4 per batch
constexpr int NCHUNK = 8;              // blocks per batch
constexpr int C4 = N4B / NCHUNK;       // 3125 vec4 per block
constexpr int THREADS = 512;           // 8 waves
constexpr int SLOTS = 7;               // ceil(3125/512) vec4 per thread
constexpr int NG = SLOTS * 8;          // 56 gathers per thread (A,B per point)
constexpr int TE = 16384;              // tile elems (64 KB)
constexpr int T = HWSZ / TE;           // 20 tiles
constexpr int NBLK = B * NCHUNK;       // 512
constexpr float INV_N = 1.0f / (float)(B * P);
constexpr float MARGIN = 1.0f;

typedef int vint4 __attribute__((ext_vector_type(4)));

__device__ __forceinline__ float loss_from(float za, float zb, int od) {
    float zd = za - zb;
    float gt = (float)(od - 1);           // {-1, 0, 1}
    float mask = fabsf(gt);               // {0, 1}
    float t = fminf(gt * zd, MARGIN);
    float l_rank = __logf(1.0f + __expf(-t));
    float l_eq = fmaxf(zd * zd, MARGIN * MARGIN);
    return mask * l_rank + (1.0f - mask) * l_eq;
}

// Stage one 64 KB tile: 8 waves x 8 loads x (64 lanes x 16 B) = 65536 B.
// LDS dest must be wave-uniform base; DMA writes lane*16 offsets (HW rule).
__device__ __forceinline__ void stage_tile(const float* __restrict__ src,
                                           float* dst, int wid, int lane) {
    #pragma unroll
    for (int l = 0; l < 8; ++l) {
        int cb = (wid * 8 + l) * 256;     // float offset of this 1 KB chunk
        __builtin_amdgcn_global_load_lds(
            (const __attribute__((address_space(1))) void*)(src + cb + lane * 4),
            (__attribute__((address_space(3))) void*)(dst + cb),
            16, 0, 0);
    }
}

__global__ __launch_bounds__(THREADS) void rdc_sweep(
        const float* __restrict__ depth,
        const vint4* __restrict__ xA, const vint4* __restrict__ yA,
        const vint4* __restrict__ xB, const vint4* __restrict__ yB,
        const vint4* __restrict__ ord,
        float* __restrict__ partials) {
    __shared__ float tiles[2][TE];        // 131072 B -> 1 block/CU
    __shared__ float wsum[8];

    // XCD pinning: j%8 ~ XCD; batch b lives on XCD b&7; its 8 chunks are
    // adjacent in dispatch so they co-sweep tiles and share L2.
    const int j = blockIdx.x;
    const int x = j & 7;
    const int g = j >> 3;                 // 0..63
    const int chunk = g & 7;
    const int b = ((g >> 3) << 3) + x;    // 0..63, on XCD b&7

    const int tid = threadIdx.x;
    const int lane = tid & 63;
    const int wid = tid >> 6;

    const float* dimg = depth + (size_t)b * HWSZ;

    // prologue: tile 0 DMA starts streaming under the index phase
    stage_tile(dimg, &tiles[0][0], wid, lane);

    // ---- index phase: 56 register-held offsets + packed ordinals ----
    const int base4 = b * N4B + chunk * C4;
    int key[NG];
    int pack[SLOTS];
    #pragma unroll
    for (int i = 0; i < SLOTS; ++i) {
        int c = i * THREADS + tid;
        if (c > C4 - 1) c = C4 - 1;       // clamp tail (i==6, tid>=53)
        int idx = base4 + c;
        vint4 xa = __builtin_nontemporal_load(&xA[idx]);
        vint4 ya = __builtin_nontemporal_load(&yA[idx]);
        vint4 xb = __builtin_nontemporal_load(&xB[idx]);
        vint4 yb = __builtin_nontemporal_load(&yB[idx]);
        vint4 od = __builtin_nontemporal_load(&ord[idx]);
        key[i*8+0] = ya.x * W + xa.x;  key[i*8+1] = yb.x * W + xb.x;
        key[i*8+2] = ya.y * W + xa.y;  key[i*8+3] = yb.y * W + xb.y;
        key[i*8+4] = ya.z * W + xa.z;  key[i*8+5] = yb.z * W + xb.z;
        key[i*8+6] = ya.w * W + xa.w;  key[i*8+7] = yb.w * W + xb.w;
        pack[i] = (od.x & 3) | ((od.y & 3) << 2) | ((od.z & 3) << 4)
                | ((od.w & 3) << 6);
    }

    float z[NG];
    #pragma unroll
    for (int k = 0; k < NG; ++k) z[k] = 0.0f;

    // ---- tile sweep: stream tile t+1 under the scan of tile t ----
    #pragma unroll 1
    for (int t = 0; t < T; ++t) {
        __syncthreads();                  // drains vmcnt: tile t in LDS; all
                                          // waves' prior ds_reads complete
        if (t + 1 < T)
            stage_tile(dimg + (t + 1) * TE, &tiles[(t + 1) & 1][0], wid, lane);

        const float* tb = &tiles[t & 1][0];
        const int t14 = t << 14;
        #pragma unroll
        for (int k = 0; k < NG; ++k) {
            unsigned rel = (unsigned)(key[k] - t14);
            if (rel < (unsigned)TE)       // exec-masked ds_read, ~3 lanes live
                z[k] = tb[rel];
        }
    }

    // ---- consume ----
    float acc = 0.0f;
    #pragma unroll
    for (int i = 0; i < SLOTS; ++i) {
        float li = 0.0f;
        #pragma unroll
        for (int q = 0; q < 4; ++q) {
            int od = (pack[i] >> (2 * q)) & 3;
            li += loss_from(z[i*8 + 2*q], z[i*8 + 2*q + 1], od);
        }
        if (i == SLOTS - 1) {
            float w6 = (tid < C4 - (SLOTS - 1) * THREADS) ? 1.0f : 0.0f;
            li *= w6;                     // zero the clamped duplicate tail
        }
        acc += li;
    }

    // ---- wave + block reduction ----
    #pragma unroll
    for (int off2 = 32; off2 > 0; off2 >>= 1)
        acc += __shfl_down(acc, off2, 64);
    if (lane == 0) wsum[wid] = acc;
    __syncthreads();
    if (wid == 0) {
        float v = (lane < 8) ? wsum[lane] : 0.0f;
        #pragma unroll
        for (int off2 = 4; off2 > 0; off2 >>= 1)
            v += __shfl_down(v, off2, 64);
        if (lane == 0) partials[j] = v;
    }
}

__global__ __launch_bounds__(256) void rdc_finalize(
        const float* __restrict__ partials, float* __restrict__ out, int n) {
    float acc = 0.0f;
    for (int k = threadIdx.x; k < n; k += 256)
        acc += partials[k];
    #pragma unroll
    for (int off = 32; off > 0; off >>= 1)
        acc += __shfl_down(acc, off, 64);
    __shared__ float wsum[4];
    int lane = threadIdx.x & 63;
    int wid  = threadIdx.x >> 6;
    if (lane == 0) wsum[wid] = acc;
    __syncthreads();
    if (wid == 0 && lane == 0)
        out[0] = (wsum[0] + wsum[1] + wsum[2] + wsum[3]) * INV_N;
}

extern "C" void kernel_launch(void* const* d_in, const int* in_sizes, int n_in,
                              void* d_out, int out_size, void* d_ws, size_t ws_size,
                              hipStream_t stream) {
    const float* depth = (const float*)d_in[0];
    const vint4* xA = (const vint4*)d_in[1];
    const vint4* yA = (const vint4*)d_in[2];
    const vint4* xB = (const vint4*)d_in[3];
    const vint4* yB = (const vint4*)d_in[4];
    const vint4* ord = (const vint4*)d_in[5];
    float* out = (float*)d_out;

    float* partials = (float*)d_ws;      // NBLK*4 = 2 KB, ws is plenty
    rdc_sweep<<<NBLK, THREADS, 0, stream>>>(depth, xA, yA, xB, yB, ord, partials);
    rdc_finalize<<<1, 256, 0, stream>>>(partials, out, NBLK);
}

// Round 2
// 309.861 us; speedup vs baseline: 1.0100x; 1.0100x over previous
//
#include <hip/hip_runtime.h>

// relative_depth_crit — R6: tile-sweep gather, branchless probe.
// R5 post-mortem: tile-sweep structure works (FETCH unchanged, stream fine)
// but the branchy `if (rel<TE) z=tb[rel]` probe compiled to per-key
// saveexec/branch/ds_read/waitcnt(0) — 56 latency-serialized LDS reads per
// tile per wave (~150cy each) = 9.7K cyc/tile = 162us. R6 makes probes
// unconditional: read tb[rel & (TE-1)] always, select with cndmask. 56
// independent ds_reads batch behind counted lgkmcnt; cost becomes DS
// throughput (~36K cyc/CU/round incl. ~2x random-bank-conflict factor),
// overlapped with VALU select (~22K/SIMD) and tile stream (~23K).
// Structural floor ~20us (mandatory 105-128 MB HBM index traffic).

constexpr int B = 64;
constexpr int H = 512;
constexpr int W = 640;
constexpr int P = 100000;
constexpr int HWSZ = H * W;            // 327680 floats = 1.31 MB per batch
constexpr int N4B = P / 4;             // 25000 vec4 per batch
constexpr int NCHUNK = 8;              // blocks per batch
constexpr int C4 = N4B / NCHUNK;       // 3125 vec4 per block
constexpr int THREADS = 512;           // 8 waves
constexpr int SLOTS = 7;               // ceil(3125/512) vec4 per thread
constexpr int NG = SLOTS * 8;          // 56 gathers per thread (A,B per point)
constexpr int TE = 16384;              // tile elems (64 KB)
constexpr int T = HWSZ / TE;           // 20 tiles
constexpr int NBLK = B * NCHUNK;       // 512
constexpr float INV_N = 1.0f / (float)(B * P);
constexpr float MARGIN = 1.0f;

typedef int vint4 __attribute__((ext_vector_type(4)));

__device__ __forceinline__ float loss_from(float za, float zb, int od) {
    float zd = za - zb;
    float gt = (float)(od - 1);           // {-1, 0, 1}
    float mask = fabsf(gt);               // {0, 1}
    float t = fminf(gt * zd, MARGIN);
    float l_rank = __logf(1.0f + __expf(-t));
    float l_eq = fmaxf(zd * zd, MARGIN * MARGIN);
    return mask * l_rank + (1.0f - mask) * l_eq;
}

// Stage one 64 KB tile: 8 waves x 8 loads x (64 lanes x 16 B) = 65536 B.
// LDS dest must be wave-uniform base; DMA writes lane*16 offsets (HW rule).
__device__ __forceinline__ void stage_tile(const float* __restrict__ src,
                                           float* dst, int wid, int lane) {
    #pragma unroll
    for (int l = 0; l < 8; ++l) {
        int cb = (wid * 8 + l) * 256;     // float offset of this 1 KB chunk
        __builtin_amdgcn_global_load_lds(
            (const __attribute__((address_space(1))) void*)(src + cb + lane * 4),
            (__attribute__((address_space(3))) void*)(dst + cb),
            16, 0, 0);
    }
}

__global__ __launch_bounds__(THREADS) void rdc_sweep(
        const float* __restrict__ depth,
        const vint4* __restrict__ xA, const vint4* __restrict__ yA,
        const vint4* __restrict__ xB, const vint4* __restrict__ yB,
        const vint4* __restrict__ ord,
        float* __restrict__ partials) {
    __shared__ float tiles[2][TE];        // 131072 B -> 1 block/CU
    __shared__ float wsum[8];

    // XCD pinning: j%8 ~ XCD; batch b lives on XCD b&7; its 8 chunks are
    // adjacent in dispatch so they co-sweep tiles and share L2.
    const int j = blockIdx.x;
    const int x = j & 7;
    const int g = j >> 3;                 // 0..63
    const int chunk = g & 7;
    const int b = ((g >> 3) << 3) + x;    // 0..63, on XCD b&7

    const int tid = threadIdx.x;
    const int lane = tid & 63;
    const int wid = tid >> 6;

    const float* dimg = depth + (size_t)b * HWSZ;

    // prologue: tile 0 DMA starts streaming under the index phase
    stage_tile(dimg, &tiles[0][0], wid, lane);

    // ---- index phase: 56 register-held offsets + packed ordinals ----
    const int base4 = b * N4B + chunk * C4;
    int key[NG];
    int pack[SLOTS];
    #pragma unroll
    for (int i = 0; i < SLOTS; ++i) {
        int c = i * THREADS + tid;
        if (c > C4 - 1) c = C4 - 1;       // clamp tail (i==6, tid>=53)
        int idx = base4 + c;
        vint4 xa = __builtin_nontemporal_load(&xA[idx]);
        vint4 ya = __builtin_nontemporal_load(&yA[idx]);
        vint4 xb = __builtin_nontemporal_load(&xB[idx]);
        vint4 yb = __builtin_nontemporal_load(&yB[idx]);
        vint4 od = __builtin_nontemporal_load(&ord[idx]);
        key[i*8+0] = ya.x * W + xa.x;  key[i*8+1] = yb.x * W + xb.x;
        key[i*8+2] = ya.y * W + xa.y;  key[i*8+3] = yb.y * W + xb.y;
        key[i*8+4] = ya.z * W + xa.z;  key[i*8+5] = yb.z * W + xb.z;
        key[i*8+6] = ya.w * W + xa.w;  key[i*8+7] = yb.w * W + xb.w;
        pack[i] = (od.x & 3) | ((od.y & 3) << 2) | ((od.z & 3) << 4)
                | ((od.w & 3) << 6);
    }

    float z[NG];
    #pragma unroll
    for (int k = 0; k < NG; ++k) z[k] = 0.0f;

    // ---- tile sweep: stream tile t+1 under the scan of tile t ----
    #pragma unroll 1
    for (int t = 0; t < T; ++t) {
        __syncthreads();                  // stage(t) visible; prev ds_reads done
        if (t + 1 < T)
            stage_tile(dimg + (t + 1) * TE, &tiles[(t + 1) & 1][0], wid, lane);

        const float* tb = &tiles[t & 1][0];
        const int t14 = t << 14;
        // Branchless probe: unconditional wrapped ds_read + cndmask select.
        // 56 independent reads batch behind counted lgkmcnt waits (no
        // per-read drain, no exec churn) -> DS throughput-bound.
        #pragma unroll
        for (int k = 0; k < NG; ++k) {
            unsigned rel = (unsigned)key[k] - (unsigned)t14;
            float v = tb[rel & (unsigned)(TE - 1)];
            z[k] = (rel < (unsigned)TE) ? v : z[k];
        }
    }

    // ---- consume ----
    float acc = 0.0f;
    #pragma unroll
    for (int i = 0; i < SLOTS; ++i) {
        float li = 0.0f;
        #pragma unroll
        for (int q = 0; q < 4; ++q) {
            int od = (pack[i] >> (2 * q)) & 3;
            li += loss_from(z[i*8 + 2*q], z[i*8 + 2*q + 1], od);
        }
        if (i == SLOTS - 1) {
            float w6 = (tid < C4 - (SLOTS - 1) * THREADS) ? 1.0f : 0.0f;
            li *= w6;                     // zero the clamped duplicate tail
        }
        acc += li;
    }

    // ---- wave + block reduction ----
    #pragma unroll
    for (int off2 = 32; off2 > 0; off2 >>= 1)
        acc += __shfl_down(acc, off2, 64);
    if (lane == 0) wsum[wid] = acc;
    __syncthreads();
    if (wid == 0) {
        float v = (lane < 8) ? wsum[lane] : 0.0f;
        #pragma unroll
        for (int off2 = 4; off2 > 0; off2 >>= 1)
            v += __shfl_down(v, off2, 64);
        if (lane == 0) partials[j] = v;
    }
}

__global__ __launch_bounds__(256) void rdc_finalize(
        const float* __restrict__ partials, float* __restrict__ out, int n) {
    float acc = 0.0f;
    for (int k = threadIdx.x; k < n; k += 256)
        acc += partials[k];
    #pragma unroll
    for (int off = 32; off > 0; off >>= 1)
        acc += __shfl_down(acc, off, 64);
    __shared__ float wsum[4];
    int lane = threadIdx.x & 63;
    int wid  = threadIdx.x >> 6;
    if (lane == 0) wsum[wid] = acc;
    __syncthreads();
    if (wid == 0 && lane == 0)
        out[0] = (wsum[0] + wsum[1] + wsum[2] + wsum[3]) * INV_N;
}

extern "C" void kernel_launch(void* const* d_in, const int* in_sizes, int n_in,
                              void* d_out, int out_size, void* d_ws, size_t ws_size,
                              hipStream_t stream) {
    const float* depth = (const float*)d_in[0];
    const vint4* xA = (const vint4*)d_in[1];
    const vint4* yA = (const vint4*)d_in[2];
    const vint4* xB = (const vint4*)d_in[3];
    const vint4* yB = (const vint4*)d_in[4];
    const vint4* ord = (const vint4*)d_in[5];
    float* out = (float*)d_out;

    float* partials = (float*)d_ws;      // NBLK*4 = 2 KB, ws is plenty
    rdc_sweep<<<NBLK, THREADS, 0, stream>>>(depth, xA, yA, xB, yB, ord, partials);
    rdc_finalize<<<1, 256, 0, stream>>>(partials, out, NBLK);
}

// Round 4
// 305.508 us; speedup vs baseline: 1.0244x; 1.0142x over previous
//
#include <hip/hip_runtime.h>

// relative_depth_crit — R7b: bucketed tile-sweep (counting sort by tile).
// Resubmission of R7: previous bench failed with "MI355X container failed
// twice" (infra acquisition failure, no kernel verdict). Kernel re-audited:
// uniform barriers only, 145.3 KB LDS < 160 KB, bucket accounting exact
// (512*48 + 53*8 = 25000 = NE), DMA buffer hazards barrier-separated.
//
// Structure: R5/R6 proved probing is O(T) DS ops per endpoint (compiler sinks
// the "branchless" probe back into the rel<TE branch -> 56 serialized
// ds_read+lgkmcnt(0) per tile = 162us). R7 buckets endpoints by tile up front
// (per-wave replica histograms + one-wave prefix scan + per-(wave,bin)
// cursors), then a 64-tile double-buffered sweep resolves each tile's exact
// bucket span: entry -> z=tile[rel] -> write z back into the cell. Owners
// remember cell indices and read back at the end. O(1) DS ops per endpoint.

constexpr int B = 64;
constexpr int H = 512;
constexpr int W = 640;
constexpr int P = 100000;
constexpr int HWSZ = H * W;            // 327680 floats = 1.31 MB per batch
constexpr int N4B = P / 4;             // 25000 vec4 per batch
constexpr int NCHUNK = 8;              // blocks per batch
constexpr int C4 = N4B / NCHUNK;       // 3125 vec4 per block
constexpr int THREADS = 512;           // 8 waves
constexpr int NWAVE = 8;
constexpr int SLOTS = 7;               // ceil(3125/512) vec4 per thread
constexpr int NG = SLOTS * 8;          // 56 endpoints per thread
constexpr int NE = C4 * 8;             // 25000 endpoints per block (exact)
constexpr int TE = 5120;               // tile elems (20 KB); 64 tiles cover image
constexpr int T = HWSZ / TE;           // 64 tiles == one wave-scan width
constexpr int NBLK = B * NCHUNK;       // 512
constexpr float INV_N = 1.0f / (float)(B * P);
constexpr float MARGIN = 1.0f;

typedef int vint4 __attribute__((ext_vector_type(4)));

__device__ __forceinline__ float loss_from(float za, float zb, int od) {
    float zd = za - zb;
    float gt = (float)(od - 1);           // {-1, 0, 1}
    float mask = fabsf(gt);               // {0, 1}
    float t = fminf(gt * zd, MARGIN);
    float l_rank = __logf(1.0f + __expf(-t));
    float l_eq = fmaxf(zd * zd, MARGIN * MARGIN);
    return mask * l_rank + (1.0f - mask) * l_eq;
}

// Stage one 20 KB tile: 20 wave-loads of 1 KB; load l handled by wave l%8
// (waves 0-3 take 3, waves 4-7 take 2). Guard is wave-uniform. LDS dest is
// wave-uniform base + lane*16 (HW rule for global_load_lds).
__device__ __forceinline__ void stage_tile(const float* __restrict__ src,
                                           float* dst, int wid, int lane) {
    #pragma unroll
    for (int r = 0; r < 3; ++r) {
        int l = wid + r * 8;
        if (l < TE / 256) {               // 20 loads
            int cb = l * 256;             // float offset of this 1 KB chunk
            __builtin_amdgcn_global_load_lds(
                (const __attribute__((address_space(1))) void*)(src + cb + lane * 4),
                (__attribute__((address_space(3))) void*)(dst + cb),
                16, 0, 0);
        }
    }
}

__global__ __launch_bounds__(THREADS) void rdc_sweep(
        const float* __restrict__ depth,
        const vint4* __restrict__ xA, const vint4* __restrict__ yA,
        const vint4* __restrict__ xB, const vint4* __restrict__ yB,
        const vint4* __restrict__ ord,
        float* __restrict__ partials) {
    __shared__ unsigned cells[NE];        // 100000 B: entry rel, then z bits
    __shared__ float tiles[2][TE];        //  40960 B, double-buffered
    __shared__ unsigned hist[NWAVE][T];   //   2048 B: per-wave histograms
    __shared__ unsigned cur[NWAVE][T];    //   2048 B: per-(wave,bin) cursors
    __shared__ unsigned startB[T + 1];    //    260 B: bin starts (excl scan)
    __shared__ float wsum[NWAVE];         // total ~145.3 KB -> 1 block/CU

    // XCD pinning: j%8 ~ XCD; batch b lives on XCD b&7; its 8 chunks co-sweep
    // tiles and share the image in that XCD's L2 (1.31 MB < 4 MB).
    const int j = blockIdx.x;
    const int x = j & 7;
    const int g = j >> 3;                 // 0..63
    const int chunk = g & 7;
    const int b = ((g >> 3) << 3) + x;    // 0..63, on XCD b&7

    const int tid = threadIdx.x;
    const int lane = tid & 63;
    const int wid = tid >> 6;

    const float* dimg = depth + (size_t)b * HWSZ;

    // prologue: tile 0 DMA streams under the index/bucketing phases
    stage_tile(dimg, &tiles[0][0], wid, lane);

    // zero replica histograms (cur is fully overwritten by the scan wave,
    // only hist needs zeroing: 512 words, 1 per thread)
    ((unsigned*)hist)[tid] = 0u;

    // ---- index phase: 56 register-held keys + packed ordinals ----
    const int base4 = b * N4B + chunk * C4;
    const bool v6 = (tid < C4 - (SLOTS - 1) * THREADS);   // slot-6 validity (tid<53)
    unsigned key[NG];                     // becomes cell-index array after placement
    int pack[SLOTS];
    #pragma unroll
    for (int i = 0; i < SLOTS; ++i) {
        int c = i * THREADS + tid;
        if (c > C4 - 1) c = C4 - 1;       // clamp tail (i==6, tid>=53)
        int idx = base4 + c;
        vint4 xa = __builtin_nontemporal_load(&xA[idx]);
        vint4 ya = __builtin_nontemporal_load(&yA[idx]);
        vint4 xb = __builtin_nontemporal_load(&xB[idx]);
        vint4 yb = __builtin_nontemporal_load(&yB[idx]);
        vint4 od = __builtin_nontemporal_load(&ord[idx]);
        key[i*8+0] = ya.x * W + xa.x;  key[i*8+1] = yb.x * W + xb.x;
        key[i*8+2] = ya.y * W + xa.y;  key[i*8+3] = yb.y * W + xb.y;
        key[i*8+4] = ya.z * W + xa.z;  key[i*8+5] = yb.z * W + xb.z;
        key[i*8+6] = ya.w * W + xa.w;  key[i*8+7] = yb.w * W + xb.w;
        pack[i] = (od.x & 3) | ((od.y & 3) << 2) | ((od.z & 3) << 4)
                | ((od.w & 3) << 6);
    }
    __syncthreads();                      // hist zeroed (also drains stage(0))

    // ---- histogram: per-wave replica rows kill cross-wave contention ----
    #pragma unroll
    for (int k = 0; k < NG; ++k) {
        if (k < 48 || v6) {               // skip clamped duplicates entirely
            unsigned bin = key[k] / (unsigned)TE;
            atomicAdd(&hist[wid][bin], 1u);
        }
    }
    __syncthreads();

    // ---- prefix scan (wave 0): global bin starts + per-wave sub-cursors ----
    if (wid == 0) {
        unsigned h[NWAVE];
        unsigned p = 0;
        #pragma unroll
        for (int w = 0; w < NWAVE; ++w) { h[w] = hist[w][lane]; }
        #pragma unroll
        for (int w = 0; w < NWAVE; ++w) { unsigned t_ = h[w]; h[w] = p; p += t_; }
        unsigned tot = p;                 // entries in bin `lane`
        unsigned inc = tot;               // inclusive scan across 64 bins
        #pragma unroll
        for (int d = 1; d < 64; d <<= 1) {
            unsigned n = __shfl_up(inc, d, 64);
            if (lane >= d) inc += n;
        }
        unsigned excl = inc - tot;
        startB[lane] = excl;
        if (lane == 63) startB[T] = excl + tot;   // == NE
        #pragma unroll
        for (int w = 0; w < NWAVE; ++w) cur[w][lane] = excl + h[w];
    }
    __syncthreads();

    // ---- placement: scatter rel-offsets into exact-sized bins ----
    #pragma unroll
    for (int k = 0; k < NG; ++k) {
        if (k < 48 || v6) {
            unsigned kk = key[k];
            unsigned bin = kk / (unsigned)TE;
            unsigned rel = kk - bin * (unsigned)TE;
            unsigned pos = atomicAdd(&cur[wid][bin], 1u);
            cells[pos] = rel;
            key[k] = pos;                 // reuse reg: key -> cell index
        } else {
            key[k] = 0u;                  // safe in-bounds readback, weight 0
        }
    }

    // ---- tile sweep: double-buffered; per tile resolve its bucket span ----
    #pragma unroll 1
    for (int t = 0; t < T; ++t) {
        __syncthreads();                  // stage(t) landed; placement/prev reads done
        if (t + 1 < T)
            stage_tile(dimg + (t + 1) * TE, &tiles[(t + 1) & 1][0], wid, lane);

        const float* tb = &tiles[t & 1][0];
        unsigned s = startB[t];
        unsigned e = startB[t + 1];
        for (unsigned u = s + tid; u < e; u += THREADS) {
            unsigned rel = cells[u];
            cells[u] = __float_as_uint(tb[rel]);
        }
    }
    __syncthreads();                      // all z writes visible

    // ---- readback + loss ----
    float acc = 0.0f;
    #pragma unroll
    for (int i = 0; i < SLOTS; ++i) {
        float li = 0.0f;
        #pragma unroll
        for (int q = 0; q < 4; ++q) {
            float za = __uint_as_float(cells[key[i*8 + 2*q]]);
            float zb = __uint_as_float(cells[key[i*8 + 2*q + 1]]);
            li += loss_from(za, zb, (pack[i] >> (2 * q)) & 3);
        }
        if (i == SLOTS - 1) li *= (v6 ? 1.0f : 0.0f);
        acc += li;
    }

    // ---- wave + block reduction ----
    #pragma unroll
    for (int off2 = 32; off2 > 0; off2 >>= 1)
        acc += __shfl_down(acc, off2, 64);
    if (lane == 0) wsum[wid] = acc;
    __syncthreads();
    if (wid == 0) {
        float v = (lane < NWAVE) ? wsum[lane] : 0.0f;
        #pragma unroll
        for (int off2 = 4; off2 > 0; off2 >>= 1)
            v += __shfl_down(v, off2, 64);
        if (lane == 0) partials[j] = v;
    }
}

__global__ __launch_bounds__(256) void rdc_finalize(
        const float* __restrict__ partials, float* __restrict__ out, int n) {
    float acc = 0.0f;
    for (int k = threadIdx.x; k < n; k += 256)
        acc += partials[k];
    #pragma unroll
    for (int off = 32; off > 0; off >>= 1)
        acc += __shfl_down(acc, off, 64);
    __shared__ float wsum[4];
    int lane = threadIdx.x & 63;
    int wid  = threadIdx.x >> 6;
    if (lane == 0) wsum[wid] = acc;
    __syncthreads();
    if (wid == 0 && lane == 0)
        out[0] = (wsum[0] + wsum[1] + wsum[2] + wsum[3]) * INV_N;
}

extern "C" void kernel_launch(void* const* d_in, const int* in_sizes, int n_in,
                              void* d_out, int out_size, void* d_ws, size_t ws_size,
                              hipStream_t stream) {
    const float* depth = (const float*)d_in[0];
    const vint4* xA = (const vint4*)d_in[1];
    const vint4* yA = (const vint4*)d_in[2];
    const vint4* xB = (const vint4*)d_in[3];
    const vint4* yB = (const vint4*)d_in[4];
    const vint4* ord = (const vint4*)d_in[5];
    float* out = (float*)d_out;

    float* partials = (float*)d_ws;      // NBLK*4 = 2 KB, ws is plenty
    rdc_sweep<<<NBLK, THREADS, 0, stream>>>(depth, xA, yA, xB, yB, ord, partials);
    rdc_finalize<<<1, 256, 0, stream>>>(partials, out, NBLK);
}